// Round 4
// baseline (135.807 us; speedup 1.0000x reference)
//
#include <hip/hip_runtime.h>
#include <hip/hip_bf16.h>

#define NROWS 8192   // 2B
#define HALFB 4096   // B
#define DIMK  256    // D
// scale folded into zn: sim_acc = cos * 2*log2(e)  ->  exp2(acc) = exp(cos/T)
#define SCALE 1.6986436f   // sqrt(2*log2(e)) = sqrt(2.8853901)

typedef __attribute__((ext_vector_type(4))) float f32x4;
typedef __attribute__((ext_vector_type(8))) short short8;

__device__ __forceinline__ unsigned short f2bf(float f) {
  unsigned u = __float_as_uint(f);
  u += 0x7fffu + ((u >> 16) & 1u);   // RNE
  return (unsigned short)(u >> 16);
}

// ---------------- kernel 1: normalize both rows of pair k + exact fp32 positive
__global__ __launch_bounds__(256) void k_normpos(const float* __restrict__ zi,
                                                 const float* __restrict__ zj,
                                                 unsigned short* __restrict__ zn,
                                                 float* __restrict__ pos) {
  const int k    = blockIdx.x * 4 + (threadIdx.x >> 6);
  const int lane = threadIdx.x & 63;
  float4 a = reinterpret_cast<const float4*>(zi + (size_t)k * DIMK)[lane];
  float4 b = reinterpret_cast<const float4*>(zj + (size_t)k * DIMK)[lane];
  float ssa = a.x * a.x + a.y * a.y + a.z * a.z + a.w * a.w;
  float ssb = b.x * b.x + b.y * b.y + b.z * b.z + b.w * b.w;
  float dot = a.x * b.x + a.y * b.y + a.z * b.z + a.w * b.w;
#pragma unroll
  for (int m = 1; m < 64; m <<= 1) {
    ssa += __shfl_xor(ssa, m, 64);
    ssb += __shfl_xor(ssb, m, 64);
    dot += __shfl_xor(dot, m, 64);
  }
  const float ra = 1.0f / fmaxf(sqrtf(ssa), 1e-8f);
  const float rb = 1.0f / fmaxf(sqrtf(ssb), 1e-8f);
  const float sa = ra * SCALE, sb = rb * SCALE;
  ushort4 oa, ob;
  oa.x = f2bf(a.x * sa); oa.y = f2bf(a.y * sa); oa.z = f2bf(a.z * sa); oa.w = f2bf(a.w * sa);
  ob.x = f2bf(b.x * sb); ob.y = f2bf(b.y * sb); ob.z = f2bf(b.z * sb); ob.w = f2bf(b.w * sb);
  reinterpret_cast<ushort4*>(zn + (size_t)k * DIMK)[lane] = oa;
  reinterpret_cast<ushort4*>(zn + (size_t)(k + HALFB) * DIMK)[lane] = ob;
  if (lane == 0) {
    const float p = dot * ra * rb * 2.0f;   // exact fp32, /T = *2
    pos[k] = p;
    pos[k + HALFB] = p;
  }
}

// ---------------- staging: 128 rows x 512B by 8 waves, XOR-swizzled global
// source, linear LDS dest via global_load_lds w=16. swz(row) = (row&7)<<4.
__device__ __forceinline__ void stage128x256(const unsigned short* __restrict__ g,
                                             unsigned short* lds, int wave, int lane) {
#pragma unroll
  for (int i = 0; i < 8; ++i) {
    const int chunk = i * 8 + wave;          // 1KB chunk index, wave-uniform
    const int row = chunk * 2 + (lane >> 5); // 2 rows (512B each) per chunk
    const int srcByte = row * 512 + (((lane & 31) << 4) ^ ((row & 7) << 4));
    __builtin_amdgcn_global_load_lds(
        (const __attribute__((address_space(1))) void*)(reinterpret_cast<const char*>(g) + srcByte),
        (__attribute__((address_space(3))) void*)(reinterpret_cast<char*>(lds) + chunk * 1024),
        16, 0, 0);
  }
}

__device__ __forceinline__ short8 ldsFrag(const unsigned short* lds, int row, int byteoff) {
  const int addr = row * 512 + (byteoff ^ ((row & 7) << 4));
  return *reinterpret_cast<const short8*>(reinterpret_cast<const char*>(lds) + addr);
}

// ---------------- kernel 2: fused sim/exp/rowsum.
// Block = 512 thr = 8 waves (4 row x 2 col). Block tile 256 rows x 1024 cols
// (8 chunks of 128). Wave tile 64x64 per chunk. A in registers (full K),
// B double-buffered in LDS (2 x 64 KB). 1 block/CU -> 2 waves/SIMD.
__global__ __launch_bounds__(512, 2) void k_simexp(const unsigned short* __restrict__ zn,
                                                   float* __restrict__ part) {
  __shared__ __align__(16) unsigned short ldsB[2][128 * DIMK];   // 2 x 64 KB

  const int tid  = threadIdx.x;
  const int lane = tid & 63;
  const int wv   = tid >> 6;
  const int wr   = wv >> 1;      // 0..3  row quarter
  const int wc   = wv & 1;       // 0..1  col half
  const int r = blockIdx.x >> 3;          // row band (256 rows)
  const int s = blockIdx.x & 7;           // col group (1024 cols)
  const int rowBase      = r << 8;
  const int colGroupBase = s << 10;

  // stage chunk 0 into buf0
  stage128x256(zn + (size_t)colGroupBase * DIMK, ldsB[0], wv, lane);

  // A fragments: this wave's 64 rows, full K=256, in registers (128 VGPRs)
  short8 af[4][8];
  const int arow0 = rowBase + wr * 64 + (lane & 15);
  const int koff  = (lane >> 4) << 3;
#pragma unroll
  for (int m = 0; m < 4; ++m)
#pragma unroll
    for (int kk = 0; kk < 8; ++kk)
      af[m][kk] = *reinterpret_cast<const short8*>(
          zn + (size_t)(arow0 + m * 16) * DIMK + kk * 32 + koff);

  float sums[4][4];
#pragma unroll
  for (int m = 0; m < 4; ++m)
#pragma unroll
    for (int rr = 0; rr < 4; ++rr) sums[m][rr] = 0.0f;

  __syncthreads();   // buf0 staged (drains vmcnt), A regs loaded

  for (int c = 0; c < 8; ++c) {
    const unsigned short* bcur = ldsB[c & 1];
    if (c < 7)   // prefetch next chunk into other buffer; drained at chunk end
      stage128x256(zn + (size_t)(colGroupBase + (c + 1) * 128) * DIMK, ldsB[(c + 1) & 1], wv, lane);

    f32x4 acc[4][4];
#pragma unroll
    for (int m = 0; m < 4; ++m)
#pragma unroll
      for (int n = 0; n < 4; ++n) acc[m][n] = (f32x4){0.f, 0.f, 0.f, 0.f};

#pragma unroll
    for (int kk = 0; kk < 8; ++kk) {
      short8 bfr[4];
      const int bo = (kk << 6) + ((lane >> 4) << 4);
#pragma unroll
      for (int n = 0; n < 4; ++n)
        bfr[n] = ldsFrag(bcur, wc * 64 + n * 16 + (lane & 15), bo);
      __builtin_amdgcn_s_setprio(1);
#pragma unroll
      for (int m = 0; m < 4; ++m)
#pragma unroll
        for (int n = 0; n < 4; ++n)
          acc[m][n] = __builtin_amdgcn_mfma_f32_16x16x32_bf16(af[m][kk], bfr[n], acc[m][n], 0, 0, 0);
      __builtin_amdgcn_s_setprio(0);
    }

    // epilogue: acc already = sim * 2*log2(e)  ->  exp2
    const int colChunk = colGroupBase + c * 128;
    if ((colChunk >> 8) == r) {   // this chunk contains diagonal cells
#pragma unroll
      for (int m = 0; m < 4; ++m) {
        const int grow = rowBase + wr * 64 + m * 16 + ((lane >> 4) << 2);
#pragma unroll
        for (int n = 0; n < 4; ++n) {
          const int gcol = colChunk + wc * 64 + n * 16 + (lane & 15);
#pragma unroll
          for (int rr = 0; rr < 4; ++rr) {
            float e = exp2f(acc[m][n][rr]);
            if (grow + rr == gcol) e = 0.0f;
            sums[m][rr] += e;
          }
        }
      }
    } else {
#pragma unroll
      for (int m = 0; m < 4; ++m)
#pragma unroll
        for (int n = 0; n < 4; ++n)
#pragma unroll
          for (int rr = 0; rr < 4; ++rr)
            sums[m][rr] += exp2f(acc[m][n][rr]);
    }

    // next chunk's staging (issued ~5000 cyc ago) must be visible to all waves
    asm volatile("s_waitcnt vmcnt(0)" ::: "memory");
    __builtin_amdgcn_s_barrier();
    __builtin_amdgcn_sched_barrier(0);
  }

  // per (colgroup, col-half) partial rowsums; every slot written exactly once
#pragma unroll
  for (int m = 0; m < 4; ++m)
#pragma unroll
    for (int rr = 0; rr < 4; ++rr) {
      float v = sums[m][rr];
      v += __shfl_xor(v, 1, 64);
      v += __shfl_xor(v, 2, 64);
      v += __shfl_xor(v, 4, 64);
      v += __shfl_xor(v, 8, 64);
      if ((lane & 15) == 0)
        part[(size_t)(s * 2 + wc) * NROWS + rowBase + wr * 64 + m * 16 + ((lane >> 4) << 2) + rr] = v;
    }
}

// ---------------- kernel 3: loss = mean(log(sum_g part[g][i]) - pos[i])
__global__ __launch_bounds__(256) void k_finalize(const float* __restrict__ part,
                                                  const float* __restrict__ pos,
                                                  float* __restrict__ out) {
  const int row = blockIdx.x * 256 + threadIdx.x;
  float d = 0.0f;
#pragma unroll
  for (int g = 0; g < 16; ++g) d += part[(size_t)g * NROWS + row];
  float v = __logf(d) - pos[row];
#pragma unroll
  for (int m = 1; m < 64; m <<= 1) v += __shfl_xor(v, m, 64);
  __shared__ float ps[4];
  if ((threadIdx.x & 63) == 0) ps[threadIdx.x >> 6] = v;
  __syncthreads();
  if (threadIdx.x == 0)
    atomicAdd(out, (ps[0] + ps[1] + ps[2] + ps[3]) * (1.0f / (float)NROWS));
}

extern "C" void kernel_launch(void* const* d_in, const int* in_sizes, int n_in,
                              void* d_out, int out_size, void* d_ws, size_t ws_size,
                              hipStream_t stream) {
  const float* zi = (const float*)d_in[0];
  const float* zj = (const float*)d_in[1];
  float* out = (float*)d_out;

  char* ws = (char*)d_ws;
  unsigned short* zn = (unsigned short*)ws;                        // 4 MiB bf16 (scaled)
  float* pos  = (float*)(ws + (size_t)NROWS * DIMK * 2);           // 32 KB
  float* part = pos + NROWS;                                       // 16 x 8192 x 4 = 512 KB

  hipMemsetAsync(out, 0, sizeof(float), stream);
  k_normpos<<<HALFB / 4, 256, 0, stream>>>(zi, zj, zn, pos);
  k_simexp<<<256, 512, 0, stream>>>(zn, part);
  k_finalize<<<NROWS / 256, 256, 0, stream>>>(part, pos, out);
}